// Round 7
// baseline (202.481 us; speedup 1.0000x reference)
//
#include <hip/hip_runtime.h>
#include <math.h>

// Problem: [16,1,1024,1024] fp32 pred/target -> scalar weighted mean-abs curvature loss.
// R14 = R13 resubmitted verbatim (R13's bench never ran: "MI355X container
// failed twice" = broker infra failure, same signature as R10's round which
// passed on resubmission; kernel has no hang/fault path -- no fences/atomics,
// no spin, in-bounds dword-aligned loads only).
// ---
// R13: block-uniform fast-path prep. Evidence ledger:
//  R7  (58us, VALUBusy 62%, VGPR 64): baseline schedule, 6 scalar loads/prep.
//  R8  (70us): manual 1-deep load pipeline REGRESSES the compiler's full-unroll
//      clustering. Don't hand-pipeline.
//  R11 (373us): per-block agent-scope fence+RMW = L2 writeback+invalidate per
//      block; never in the per-block path of a cache-reliant kernel.
//  R12 (91us, VGPR 144, occ 10.9%): VGPR>64 + 4-blocks/CU grid collapses
//      residency to ~1 wave/SIMD; occupancy is the binding resource.
// R13 change: tiles 1,2 (half of all blocks) have no x-edge -> one dwordx4 at
// x-1 per image yields all 3 taps {L,C,R}: 2 VMEM/prep instead of 6 (3x fewer
// latency events + L1 requests), and the 4 packed edge-selects fold away.
// Edge tiles (tx==0,3) keep the R7 prep VERBATIM. Branch is block-uniform.
// Grid/VGPR/ROWS/unroll untouched (4096 blocks, 256 thr, 1 col/thread).
// Numerics: interior path computes bitwise-identical values (same combine,
// same order; dropped masks were no-ops there); edges unchanged -> absmax 0.0.

constexpr int IMG_B = 16;
constexpr int IMG_H = 1024;
constexpr int IMG_W = 1024;
constexpr int ROWS  = 16;                      // rows per block
constexpr int BLOCK = 256;                     // 256 threads = 256 columns
constexpr int TILES_X = IMG_W / BLOCK;         // 4
constexpr int TILES_Y = IMG_H / ROWS;          // 64
constexpr int NBLOCKS = IMG_B * TILES_Y * TILES_X;  // 4096
constexpr float EPS = 1e-8f;

// scale constants: p = gx/80, q = gy/80, r = rxx/300, 2s = sxy/200, t = tyy/300
constexpr float A2 = 1.0f / 6400.0f;
constexpr float Bc = 1.0f / 300.0f;
constexpr float C2 = 1.0f / 200.0f;

typedef float f2v __attribute__((ext_vector_type(2)));
// 4B-aligned 16B vector: gfx9+ global VMEM supports dword-aligned dwordx4;
// aligned(4) keeps the C++ side honest while still emitting one load.
typedef float f4v __attribute__((ext_vector_type(4), aligned(4)));

__device__ __forceinline__ f2v pk_fma(f2v a, f2v b, f2v c) {
    return __builtin_elementwise_fma(a, b, c);
}

// rolling-window row state, lanes = {pred, target}
struct Rowv { f2v hx, hs, rs; };

// prof/plan true scale; mean2 = 2*mean (weight absorbs the 1/2). Lane-parallel
// over {pred, target}; transcendentals + flat-mask stay per-component.
__device__ __forceinline__ void curv_pair(const Rowv& a, const Rowv& b, const Rowv& c,
                                          f2v& prof, f2v& plan, f2v& mean2)
{
    const f2v A2f = {A2, A2}, Bcf = {Bc, Bc}, C2f = {C2, C2};
    const f2v m3  = {-3.0f, -3.0f}, two = {2.0f, 2.0f};
    const f2v epsf = {EPS, EPS};

    const f2v gx  = pk_fma(two, b.hx, a.hx + c.hx);   // sobel_x (raw)
    const f2v gy  = c.hs - a.hs;                      // sobel_y (raw)
    const f2v tot = (a.rs + c.rs) + b.rs;             // 3x3 sum
    const f2v H   = (a.hs + c.hs) + b.hs;
    const f2v rxx = pk_fma(m3, H - tot, tot);         // k_xx * 3 (raw)
    const f2v tyy = pk_fma(m3, b.rs, tot);            // k_yy * 3 (raw)
    const f2v sxy = a.hx - c.hx;                      // k_xy * 4 (raw)

    const f2v gx2 = gx * gx, gy2 = gy * gy, gxgy = gx * gy;
    const f2v g2  = gx2 + gy2;
    const f2v d1  = A2f * g2;                         // p^2 + q^2
    const f2v od  = d1 + f2v{1.0f, 1.0f};

    f2v rsq_od, sq_d1;                                // per-component transcendentals
    rsq_od.x = __builtin_amdgcn_rsqf(od.x);
    rsq_od.y = __builtin_amdgcn_rsqf(od.y);
    sq_d1.x  = __builtin_amdgcn_sqrtf(d1.x);
    sq_d1.y  = __builtin_amdgcn_sqrtf(d1.y);
    const f2v sq_od = od * rsq_od;                    // sqrt(1+d1)

    const f2v h1    = pk_fma(tyy, gy2, rxx * gx2);
    const f2v h3    = pk_fma(tyy, gx2, rxx * gy2);
    const f2v h2c   = C2f * (sxy * gxgy);
    const f2v nprof = A2f * pk_fma(Bcf, h1,  h2c);    // r*p2+2s*pq+t*q2
    const f2v nplan = A2f * pk_fma(Bcf, h3, -h2c);    // r*q2-2s*pq+t*p2
    const f2v mnum  = pk_fma(Bcf, rxx + tyy, nplan);  // (1+q2)r-2pq*s+(1+p2)t

    const f2v den_p = pk_fma(d1, sq_od, epsf);        // d1*sqrt(1+d1)+EPS
    const f2v den_l = pk_fma(d1, sq_d1, epsf);        // d1^1.5+EPS
    const f2v plprod = den_p * den_l;                 // >=1e-16, no underflow
    f2v rcpPL;
    rcpPL.x = __builtin_amdgcn_rcpf(plprod.x);
    rcpPL.y = __builtin_amdgcn_rcpf(plprod.y);

    prof  = (nprof * den_l) * rcpPL;
    plan  = (nplan * den_p) * rcpPL;
    mean2 = mnum * ((rsq_od * rsq_od) * rsq_od);      // mnum/od^1.5 = 2*mean
    // flat mask per component
    prof.x = (d1.x < EPS) ? 0.0f : prof.x;
    prof.y = (d1.y < EPS) ? 0.0f : prof.y;
    plan.x = (d1.x < EPS) ? 0.0f : plan.x;
    plan.y = (d1.y < EPS) ? 0.0f : plan.y;
}

__global__ __launch_bounds__(BLOCK) void curv_loss_main(
    const float* __restrict__ pred, const float* __restrict__ targ,
    float* __restrict__ blocksums)
{
    const int tid = threadIdx.x;
    const int b   = blockIdx.x;
    const int tx  = b & (TILES_X - 1);
    const int ty  = (b >> 2) & (TILES_Y - 1);
    const int img = b >> 8;                   // 4*64 = 256 blocks per image
    const int y0  = ty * ROWS;
    const int x   = tx * BLOCK + tid;

    const size_t ibase = (size_t)img * (size_t)(IMG_H * IMG_W);
    const char* __restrict__ Pc = (const char*)(pred + ibase);
    const char* __restrict__ Tc = (const char*)(targ + ibase);

    // block-uniform: interior tiles (tx==1,2) have 1 <= x <= 1022 for all lanes
    const bool interior = (tx != 0) && (tx != TILES_X - 1);

    const bool xm = (x > 0);
    const bool xp = (x < IMG_W - 1);
    // edge-path per-tap byte offsets (clamped at image edge; value masked to 0)
    const int eL = (x + (xm ? -1 : 0)) << 2;
    const int eC = x << 2;
    const int eR = (x + (xp ? +1 : 0)) << 2;
    // interior-path base: one dwordx4 at x-1 covers taps {L,C,R} (+1 unused)
    const int eB = (x - 1) << 2;

    // prep one row into the rolling window; vo = row byte offset (y<<12)
    auto prep = [&](int y, Rowv& o) {
        if ((unsigned)y < (unsigned)IMG_H) {          // block-uniform branch
            const int vo = y << 12;
            f2v w0, w1, w2;
            if (interior) {                           // block-uniform branch
                const f4v pv = *(const f4v*)(Pc + vo + eB);
                const f4v tv = *(const f4v*)(Tc + vo + eB);
                w0 = f2v{pv.x, tv.x};                 // x-1
                w1 = f2v{pv.y, tv.y};                 // x
                w2 = f2v{pv.z, tv.z};                 // x+1
            } else {                                  // R7 path verbatim
                const float pl = *(const float*)(Pc + vo + eL);
                const float tl = *(const float*)(Tc + vo + eL);
                const float pc = *(const float*)(Pc + vo + eC);
                const float tc = *(const float*)(Tc + vo + eC);
                const float pr = *(const float*)(Pc + vo + eR);
                const float tr = *(const float*)(Tc + vo + eR);
                w0 = f2v{xm ? pl : 0.0f, xm ? tl : 0.0f};
                w1 = f2v{pc, tc};
                w2 = f2v{xp ? pr : 0.0f, xp ? tr : 0.0f};
            }
            const f2v e = w0 + w2;
            o.hx = w2 - w0;
            o.hs = pk_fma(f2v{2.0f, 2.0f}, w1, e);
            o.rs = e + w1;
        } else {                                       // zero 'SAME' padding row
            o.hx = f2v{0.0f, 0.0f}; o.hs = f2v{0.0f, 0.0f}; o.rs = f2v{0.0f, 0.0f};
        }
    };

    Rowv w[3];
    prep(y0 - 1, w[0]);
    prep(y0,     w[1]);

    float acc = 0.0f;
#pragma unroll
    for (int i = 0; i < ROWS; ++i) {
        const int ia = i % 3, ib = (i + 1) % 3, ic = (i + 2) % 3;
        prep(y0 + i + 1, w[ic]);
        f2v prof, plan, mean2;
        curv_pair(w[ia], w[ib], w[ic], prof, plan, mean2);
        acc = fmaf(0.5f, fabsf(prof.x  - prof.y),  acc);
        acc = fmaf(0.3f, fabsf(plan.x  - plan.y),  acc);
        acc = fmaf(0.1f, fabsf(mean2.x - mean2.y), acc);  // 0.2*|dMean|
    }

    // wave64 reduce, then cross-wave via LDS
#pragma unroll
    for (int off = 32; off > 0; off >>= 1) acc += __shfl_down(acc, off, 64);
    __shared__ float ws[BLOCK / 64];
    const int lane = tid & 63, wid = tid >> 6;
    if (lane == 0) ws[wid] = acc;
    __syncthreads();
    if (tid == 0)
        blocksums[b] = (ws[0] + ws[1]) + (ws[2] + ws[3]);
}

__global__ __launch_bounds__(BLOCK) void curv_loss_final(
    const float* __restrict__ blocksums, float* __restrict__ out)
{
    const int tid = threadIdx.x;
    float v = 0.0f;
#pragma unroll
    for (int i = 0; i < NBLOCKS / BLOCK; ++i) v += blocksums[i * BLOCK + tid];
#pragma unroll
    for (int off = 32; off > 0; off >>= 1) v += __shfl_down(v, off, 64);
    __shared__ float ws[BLOCK / 64];
    const int lane = tid & 63, wid = tid >> 6;
    if (lane == 0) ws[wid] = v;
    __syncthreads();
    if (tid == 0) {
        const float tot = (ws[0] + ws[1]) + (ws[2] + ws[3]);
        out[0] = tot * (1.0f / (float)(IMG_B * IMG_H * IMG_W));
    }
}

extern "C" void kernel_launch(void* const* d_in, const int* in_sizes, int n_in,
                              void* d_out, int out_size, void* d_ws, size_t ws_size,
                              hipStream_t stream)
{
    const float* pred = (const float*)d_in[0];
    const float* targ = (const float*)d_in[1];
    float* out = (float*)d_out;
    float* blocksums = (float*)d_ws;   // 4096 floats; every slot written each call

    curv_loss_main<<<NBLOCKS, BLOCK, 0, stream>>>(pred, targ, blocksums);
    curv_loss_final<<<1, BLOCK, 0, stream>>>(blocksums, out);
}

// Round 8
// 152.862 us; speedup vs baseline: 1.3246x; 1.3246x over previous
//
#include <hip/hip_runtime.h>
#include <math.h>

// Problem: [16,1,1024,1024] fp32 pred/target -> scalar weighted mean-abs curvature loss.
// R15: R7 body BYTE-IDENTICAL; only change = __launch_bounds__(256, 4) on the
// main kernel (VGPR cap 64 -> 128) to let the compiler deepen its own load
// lookahead. Evidence ledger:
//  R7  (58us, VALUBusy 62%, VGPR 64, occ ~2.7-3.4 waves/SIMD): baseline.
//  R8  (70us): manual 1-deep load pipeline REGRESSES the compiler schedule.
//  R11 (373us): per-block agent-scope fence+RMW = L2 wb+inv per block. Poison.
//  R12 (91us): VGPR 144 *with* 4x-coarser grid (1024 blocks) -- confounded
//      register test; residency collapsed.
//  R14 (103us): overlapping 4B-aligned dwordx4 -> TA request-splitting; per-lane
//      post-split REQUESTS are the cost, not instruction count.
// All four restructures preserved: R7's gap = 38% stall at VGPR=64. Compiler's
// default heuristic targets 8 waves/SIMD (VGPR 64) but measured residency is
// ~3; the unused headroom can hold 2-3 iterations of load lookahead (~500-700
// cyc cover vs ~220 cyc/iter). R15 is the UNCONFOUNDED version of R12's
// register axis: grid stays 4096 (16 blocks/CU), 1 col/thread, body untouched.
// Decision rule: VGPR up + time down => sweep bound next; VGPR up + time flat
// => stall is structural, accept ~58us main; VGPR still 64 => void, same.
// Numerics identical -> absmax 0.0.

constexpr int IMG_B = 16;
constexpr int IMG_H = 1024;
constexpr int IMG_W = 1024;
constexpr int ROWS  = 16;                      // rows per block
constexpr int BLOCK = 256;                     // 256 threads = 256 columns
constexpr int TILES_X = IMG_W / BLOCK;         // 4
constexpr int TILES_Y = IMG_H / ROWS;          // 64
constexpr int NBLOCKS = IMG_B * TILES_Y * TILES_X;  // 4096
constexpr float EPS = 1e-8f;

// scale constants: p = gx/80, q = gy/80, r = rxx/300, 2s = sxy/200, t = tyy/300
constexpr float A2 = 1.0f / 6400.0f;
constexpr float Bc = 1.0f / 300.0f;
constexpr float C2 = 1.0f / 200.0f;

typedef float f2v __attribute__((ext_vector_type(2)));

__device__ __forceinline__ f2v pk_fma(f2v a, f2v b, f2v c) {
    return __builtin_elementwise_fma(a, b, c);
}

// rolling-window row state, lanes = {pred, target}
struct Rowv { f2v hx, hs, rs; };

// prof/plan true scale; mean2 = 2*mean (weight absorbs the 1/2). Lane-parallel
// over {pred, target}; transcendentals + flat-mask stay per-component.
__device__ __forceinline__ void curv_pair(const Rowv& a, const Rowv& b, const Rowv& c,
                                          f2v& prof, f2v& plan, f2v& mean2)
{
    const f2v A2f = {A2, A2}, Bcf = {Bc, Bc}, C2f = {C2, C2};
    const f2v m3  = {-3.0f, -3.0f}, two = {2.0f, 2.0f};
    const f2v epsf = {EPS, EPS};

    const f2v gx  = pk_fma(two, b.hx, a.hx + c.hx);   // sobel_x (raw)
    const f2v gy  = c.hs - a.hs;                      // sobel_y (raw)
    const f2v tot = (a.rs + c.rs) + b.rs;             // 3x3 sum
    const f2v H   = (a.hs + c.hs) + b.hs;
    const f2v rxx = pk_fma(m3, H - tot, tot);         // k_xx * 3 (raw)
    const f2v tyy = pk_fma(m3, b.rs, tot);            // k_yy * 3 (raw)
    const f2v sxy = a.hx - c.hx;                      // k_xy * 4 (raw)

    const f2v gx2 = gx * gx, gy2 = gy * gy, gxgy = gx * gy;
    const f2v g2  = gx2 + gy2;
    const f2v d1  = A2f * g2;                         // p^2 + q^2
    const f2v od  = d1 + f2v{1.0f, 1.0f};

    f2v rsq_od, sq_d1;                                // per-component transcendentals
    rsq_od.x = __builtin_amdgcn_rsqf(od.x);
    rsq_od.y = __builtin_amdgcn_rsqf(od.y);
    sq_d1.x  = __builtin_amdgcn_sqrtf(d1.x);
    sq_d1.y  = __builtin_amdgcn_sqrtf(d1.y);
    const f2v sq_od = od * rsq_od;                    // sqrt(1+d1)

    const f2v h1    = pk_fma(tyy, gy2, rxx * gx2);
    const f2v h3    = pk_fma(tyy, gx2, rxx * gy2);
    const f2v h2c   = C2f * (sxy * gxgy);
    const f2v nprof = A2f * pk_fma(Bcf, h1,  h2c);    // r*p2+2s*pq+t*q2
    const f2v nplan = A2f * pk_fma(Bcf, h3, -h2c);    // r*q2-2s*pq+t*p2
    const f2v mnum  = pk_fma(Bcf, rxx + tyy, nplan);  // (1+q2)r-2pq*s+(1+p2)t

    const f2v den_p = pk_fma(d1, sq_od, epsf);        // d1*sqrt(1+d1)+EPS
    const f2v den_l = pk_fma(d1, sq_d1, epsf);        // d1^1.5+EPS
    const f2v plprod = den_p * den_l;                 // >=1e-16, no underflow
    f2v rcpPL;
    rcpPL.x = __builtin_amdgcn_rcpf(plprod.x);
    rcpPL.y = __builtin_amdgcn_rcpf(plprod.y);

    prof  = (nprof * den_l) * rcpPL;
    plan  = (nplan * den_p) * rcpPL;
    mean2 = mnum * ((rsq_od * rsq_od) * rsq_od);      // mnum/od^1.5 = 2*mean
    // flat mask per component
    prof.x = (d1.x < EPS) ? 0.0f : prof.x;
    prof.y = (d1.y < EPS) ? 0.0f : prof.y;
    plan.x = (d1.x < EPS) ? 0.0f : plan.x;
    plan.y = (d1.y < EPS) ? 0.0f : plan.y;
}

__global__ __launch_bounds__(BLOCK, 4) void curv_loss_main(
    const float* __restrict__ pred, const float* __restrict__ targ,
    float* __restrict__ blocksums)
{
    const int tid = threadIdx.x;
    const int b   = blockIdx.x;
    const int tx  = b & (TILES_X - 1);
    const int ty  = (b >> 2) & (TILES_Y - 1);
    const int img = b >> 8;                   // 4*64 = 256 blocks per image
    const int y0  = ty * ROWS;
    const int x   = tx * BLOCK + tid;

    const size_t ibase = (size_t)img * (size_t)(IMG_H * IMG_W);
    const char* __restrict__ Pc = (const char*)(pred + ibase);
    const char* __restrict__ Tc = (const char*)(targ + ibase);

    const bool xm = (x > 0);
    const bool xp = (x < IMG_W - 1);
    // per-tap byte offsets within a row (clamped at image edge; value masked to 0)
    const int eL = (x + (xm ? -1 : 0)) << 2;
    const int eC = x << 2;
    const int eR = (x + (xp ? +1 : 0)) << 2;

    // prep one row into the rolling window; vo = row byte offset (y<<12)
    auto prep = [&](int y, Rowv& o) {
        if ((unsigned)y < (unsigned)IMG_H) {          // block-uniform branch
            const int vo = y << 12;
            const float pl = *(const float*)(Pc + vo + eL);
            const float tl = *(const float*)(Tc + vo + eL);
            const float pc = *(const float*)(Pc + vo + eC);
            const float tc = *(const float*)(Tc + vo + eC);
            const float pr = *(const float*)(Pc + vo + eR);
            const float tr = *(const float*)(Tc + vo + eR);
            const f2v w0 = {xm ? pl : 0.0f, xm ? tl : 0.0f};
            const f2v w1 = {pc, tc};
            const f2v w2 = {xp ? pr : 0.0f, xp ? tr : 0.0f};
            const f2v e = w0 + w2;
            o.hx = w2 - w0;
            o.hs = pk_fma(f2v{2.0f, 2.0f}, w1, e);
            o.rs = e + w1;
        } else {                                       // zero 'SAME' padding row
            o.hx = f2v{0.0f, 0.0f}; o.hs = f2v{0.0f, 0.0f}; o.rs = f2v{0.0f, 0.0f};
        }
    };

    Rowv w[3];
    prep(y0 - 1, w[0]);
    prep(y0,     w[1]);

    float acc = 0.0f;
#pragma unroll
    for (int i = 0; i < ROWS; ++i) {
        const int ia = i % 3, ib = (i + 1) % 3, ic = (i + 2) % 3;
        prep(y0 + i + 1, w[ic]);
        f2v prof, plan, mean2;
        curv_pair(w[ia], w[ib], w[ic], prof, plan, mean2);
        acc = fmaf(0.5f, fabsf(prof.x  - prof.y),  acc);
        acc = fmaf(0.3f, fabsf(plan.x  - plan.y),  acc);
        acc = fmaf(0.1f, fabsf(mean2.x - mean2.y), acc);  // 0.2*|dMean|
    }

    // wave64 reduce, then cross-wave via LDS
#pragma unroll
    for (int off = 32; off > 0; off >>= 1) acc += __shfl_down(acc, off, 64);
    __shared__ float ws[BLOCK / 64];
    const int lane = tid & 63, wid = tid >> 6;
    if (lane == 0) ws[wid] = acc;
    __syncthreads();
    if (tid == 0)
        blocksums[b] = (ws[0] + ws[1]) + (ws[2] + ws[3]);
}

__global__ __launch_bounds__(BLOCK) void curv_loss_final(
    const float* __restrict__ blocksums, float* __restrict__ out)
{
    const int tid = threadIdx.x;
    float v = 0.0f;
#pragma unroll
    for (int i = 0; i < NBLOCKS / BLOCK; ++i) v += blocksums[i * BLOCK + tid];
#pragma unroll
    for (int off = 32; off > 0; off >>= 1) v += __shfl_down(v, off, 64);
    __shared__ float ws[BLOCK / 64];
    const int lane = tid & 63, wid = tid >> 6;
    if (lane == 0) ws[wid] = v;
    __syncthreads();
    if (tid == 0) {
        const float tot = (ws[0] + ws[1]) + (ws[2] + ws[3]);
        out[0] = tot * (1.0f / (float)(IMG_B * IMG_H * IMG_W));
    }
}

extern "C" void kernel_launch(void* const* d_in, const int* in_sizes, int n_in,
                              void* d_out, int out_size, void* d_ws, size_t ws_size,
                              hipStream_t stream)
{
    const float* pred = (const float*)d_in[0];
    const float* targ = (const float*)d_in[1];
    float* out = (float*)d_out;
    float* blocksums = (float*)d_ws;   // 4096 floats; every slot written each call

    curv_loss_main<<<NBLOCKS, BLOCK, 0, stream>>>(pred, targ, blocksums);
    curv_loss_final<<<1, BLOCK, 0, stream>>>(blocksums, out);
}